// Round 7
// baseline (103.502 us; speedup 1.0000x reference)
//
#include <hip/hip_runtime.h>
#include <hip/hip_bf16.h>
#include <math.h>

// Problem constants (from reference setup_inputs):
//   support [25, 2560] fp32, query [4096, 2560] fp32, n_way=5, k_shot=5
//   out [4096, 5] fp32 = -dist.reshape(4096,5,5).sum(-1)
//   dist[q][s] = || support[s] - query[q] + 1e-6 ||_2
// Strategy: dist^2 = ||s+eps||^2 - 2*(s.q + eps*sum(q)) + ||q||^2
//   -> 1 FMA per (q,s,d) element.
//
// R6 post-mortem: no spill, kernel ~28 us vs ~10 us L1/L2-BW floor. Suspected
// limiter: in-order vmcnt retirement (m135) -- query loads (HBM ~900cyc) are
// issued before support loads (L2 ~200cyc) each iter, so every support-FMA
// s_waitcnt is gated on the query HBM round-trip. R7: query goes to LDS via
// global_load_lds (async, double-buffered, issued at iteration END so it sits
// BEHIND support loads in the vmcnt queue); q consumed via ds_read (lgkmcnt,
// independent counter). sg-wave pairs share the staged q chunk (q L1 traffic
// halves); q-buffer aliases the reduction buffer (LDS stays ~33 KB -> 4
// blocks/CU, 4 waves/SIMD).

#define EPS 1e-6f
#define D 2560
#define NSUP 25
#define NQ 4096
#define NWAY 5
#define KSHOT 5

#define QR 4           // query rows per block
#define BT 256         // 4 waves: (sg, dg)
#define KITER 5        // d-chunks per wave (10 total, alternating by dg)
#define NSL 13         // supports per sup-group (sg0: 0-12, sg1: 12-24)
#define NACC 60        // 52 dots + 4 sumq + 4 normq
#define PH 30          // reduction values per phase
#define STRIDE 31      // odd -> <=2-way LDS bank aliasing (free)

// async global->LDS: lane i's 16 B land at lds_base + 16*i (wave-uniform base)
__device__ __forceinline__ void async_q16(const float* gp, float* lp) {
    __builtin_amdgcn_global_load_lds(
        (const __attribute__((address_space(1))) void*)gp,
        (__attribute__((address_space(3))) void*)lp,
        16, 0, 0);
}

// ---- prep: ns[s] = || support[s] + eps ||^2  (25 floats into workspace) ----
__global__ void prep_kernel(const float* __restrict__ sup, float* __restrict__ ns) {
    const int s = blockIdx.x;
    const int t = threadIdx.x;  // 256 threads
    float p = 0.f;
    #pragma unroll
    for (int k = 0; k < 10; ++k) {
        float v = sup[s * D + t + 256 * k] + EPS;
        p += v * v;
    }
    __shared__ float red[256];
    red[t] = p;
    __syncthreads();
    for (int off = 128; off > 0; off >>= 1) {
        if (t < off) red[t] += red[t + off];
        __syncthreads();
    }
    if (t == 0) ns[s] = red[0];
}

// ---- main: QR query rows per block; waves = (sup-group sg) x (d-half dg) ----
__global__ __launch_bounds__(BT, 2)   // NOT (BT,4): that forces a 64-VGPR budget and spills
void pairwise_kernel(const float* __restrict__ q, const float* __restrict__ sup,
                     const float* __restrict__ ns, float* __restrict__ out) {
    const int t = threadIdx.x;
    const int lane = t & 63;
    const int wave = t >> 6;          // 0..3
    const int sg = wave >> 1;         // support group: 0 -> sups 0-12, 1 -> 12-24
    const int dg = wave & 1;          // d-interleave: chunks k = 2j+dg
    const int row0 = blockIdx.x * QR;
    const int sup_base = sg * (NSL - 1);   // 0 or 12

    // smem is time-multiplexed: during the k-loop, floats [0..4096) hold the
    // query double-buffer qbuf[2][2 dg][QR*256]; after the loop (barrier-
    // separated) it becomes the 256x31 reduction transpose buffer.
    __shared__ float smem[BT * STRIDE];   // 31744 B
    __shared__ float red0[NACC];          // sg0 sums (sups 0-12 + full-D q stats)
    __shared__ float red1[NACC];          // sg1 sums (sups 12-24)
    __shared__ float dist[100];

    // prologue: stage q chunk j=0 for this dg (one wave per dg buffer)
    if (sg == 0) {
        #pragma unroll
        for (int r = 0; r < QR; ++r)
            async_q16(&q[(row0 + r) * D + 256 * dg + 4 * lane],
                      &smem[dg * 1024 + r * 256]);
    }
    __syncthreads();   // drains glds (vmcnt0 before barrier)

    // acc[r*13+j] = partial dot(support[sup_base+j], query[row0+r])
    // acc[52+r]   = partial sum(query[row0+r]); acc[56+r] = partial ||q_r||^2
    // ALL acc indices must be compile-time constants (SROA -> registers).
    float acc[NACC];
    #pragma unroll
    for (int i = 0; i < NACC; ++i) acc[i] = 0.f;

    #pragma unroll 1                      // do NOT unroll: bounds register pressure
    for (int j = 0; j < KITER; ++j) {
        const int cur = j & 1, nxt = cur ^ 1;
        const int idx = 4 * lane + 512 * j + 256 * dg;  // support float index, 16B-aligned

        // query from LDS (lgkmcnt path -- independent of support's vmcnt)
        float4 qv[QR];
        #pragma unroll
        for (int r = 0; r < QR; ++r)
            qv[r] = *reinterpret_cast<const float4*>(
                        &smem[(cur * 2 + dg) * 1024 + r * 256 + 4 * lane]);
        #pragma unroll
        for (int r = 0; r < QR; ++r) {
            acc[52 + r] += (qv[r].x + qv[r].y) + (qv[r].z + qv[r].w);
            acc[56 + r] += qv[r].x * qv[r].x + qv[r].y * qv[r].y
                         + qv[r].z * qv[r].z + qv[r].w * qv[r].w;
        }

        // support: 13 rows in groups of 4 (4,4,4,1). Only support loads are in
        // the vmcnt queue here -> FMA waits are fast L2-hit waits.
        #pragma unroll
        for (int g = 0; g < NSL; g += 4) {
            const int ge = (g + 4 < NSL) ? g + 4 : NSL;
            float4 a4[4];
            #pragma unroll
            for (int jj = g; jj < ge; ++jj)
                a4[jj - g] = *reinterpret_cast<const float4*>(&sup[(sup_base + jj) * D + idx]);
            #pragma unroll
            for (int jj = g; jj < ge; ++jj) {
                #pragma unroll
                for (int r = 0; r < QR; ++r) {
                    acc[r * NSL + jj] += a4[jj - g].x * qv[r].x + a4[jj - g].y * qv[r].y
                                       + a4[jj - g].z * qv[r].z + a4[jj - g].w * qv[r].w;
                }
            }
        }

        // prefetch next q chunk LAST (newest in vmcnt queue -> never gates the
        // support waits above); landed by the barrier's vmcnt(0) drain.
        if (j < KITER - 1 && sg == 0) {
            #pragma unroll
            for (int r = 0; r < QR; ++r)
                async_q16(&q[(row0 + r) * D + 512 * (j + 1) + 256 * dg + 4 * lane],
                          &smem[(nxt * 2 + dg) * 1024 + r * 256]);
        }
        __syncthreads();
    }

    // ---- cross-thread reduction: LDS transpose, 2 phases of 30 columns ----
    // Phase loop fully unrolled: runtime p would make acc[p*PH+v] a dynamic
    // register-array index -> SROA fails -> scratch spill (R2-R5's bug).
    #pragma unroll
    for (int p = 0; p < 2; ++p) {
        #pragma unroll
        for (int v = 0; v < PH; ++v) smem[t * STRIDE + v] = acc[p * PH + v];
        __syncthreads();
        // wave0 lanes reduce sg0 (rows 0-127), wave2 lanes reduce sg1 (rows 128-255)
        if ((wave == 0 || wave == 2) && lane < PH) {
            const int base = (wave >> 1) * 128;
            float s0 = 0.f, s1 = 0.f, s2 = 0.f, s3 = 0.f;
            for (int i = 0; i < 128; i += 4) {
                s0 += smem[(base + i + 0) * STRIDE + lane];
                s1 += smem[(base + i + 1) * STRIDE + lane];
                s2 += smem[(base + i + 2) * STRIDE + lane];
                s3 += smem[(base + i + 3) * STRIDE + lane];
            }
            const float tot = (s0 + s1) + (s2 + s3);
            if (wave == 0) red0[p * PH + lane] = tot;
            else           red1[p * PH + lane] = tot;
        }
        __syncthreads();
    }

    // ---- epilogue: dist = sqrt(ns + ||q||^2 - 2*(dot + eps*sumq)) ----
    if (t < 100) {
        const int r = t / NSUP, s = t % NSUP;
        const float dot = (s < NSL) ? red0[r * NSL + s] : red1[r * NSL + (s - (NSL - 1))];
        const float d2 = ns[s] + red0[56 + r] - 2.f * (dot + EPS * red0[52 + r]);
        dist[t] = sqrtf(fmaxf(d2, 0.f));
    }
    __syncthreads();
    if (t < QR * NWAY) {
        const int r = t / NWAY, w = t % NWAY;
        float sc = 0.f;
        #pragma unroll
        for (int j = 0; j < KSHOT; ++j) sc += dist[r * NSUP + w * KSHOT + j];
        out[(row0 + r) * NWAY + w] = -sc;
    }
}

extern "C" void kernel_launch(void* const* d_in, const int* in_sizes, int n_in,
                              void* d_out, int out_size, void* d_ws, size_t ws_size,
                              hipStream_t stream) {
    const float* support = (const float*)d_in[0];
    const float* query   = (const float*)d_in[1];
    // d_in[2]=n_way(5), d_in[3]=k_shot(5): hardcoded per setup_inputs.
    float* out = (float*)d_out;
    float* ns  = (float*)d_ws;   // 25 floats of scratch

    prep_kernel<<<NSUP, 256, 0, stream>>>(support, ns);
    pairwise_kernel<<<NQ / QR, BT, 0, stream>>>(query, support, ns, out);
}